// Round 4
// baseline (2423.946 us; speedup 1.0000x reference)
//
#include <hip/hip_runtime.h>
#include <hip/hip_bf16.h>

// GCN: 6 conv layers (2->32->64->64x4), segment-max pool to 512 graphs, FC head.
// Input dtypes are DETECTED at runtime (flags in ws): floats may be f32 or bf16,
// ints may be int32 or int64. Everything is normalized to f32/int32 in ws.

#define N_NODES 50000
#define N_GRAPHS 512
#define WIDTH 64

// weight offsets (floats) inside the converted-weights block
#define OFF_W1   0
#define OFF_B1   64
#define OFF_W2   96
#define OFF_B2   2144
#define OFF_CW   2208
#define OFF_CB   18592
#define OFF_FW1  18848
#define OFF_FB1  22944
#define OFF_FW2  23008
#define OFF_FB2  25056
#define OFF_FW3  25088
#define OFF_FB3  25152
#define TOTAL_W  25154
#define TOTAL_X  100000
#define TOTAL_CVT (TOTAL_X + TOTAL_W)

__device__ __forceinline__ float elu_f(float x) {
    return x > 0.f ? x : expm1f(x);
}

__device__ __forceinline__ unsigned fmono(float v) {
    unsigned b = __float_as_uint(v);
    return (b & 0x80000000u) ? ~b : (b | 0x80000000u);
}
__device__ __forceinline__ float funmono(unsigned m) {
    unsigned b = (m & 0x80000000u) ? (m ^ 0x80000000u) : ~m;
    return __uint_as_float(b);
}

// ---- dtype detection: flags[0]=ints-are-int64, flags[1]=floats-are-bf16 ----
__global__ void detect_kernel(const void* __restrict__ eidx,
                              const void* __restrict__ x,
                              int* __restrict__ flags) {
    const int* e32 = (const int*)eidx;
    // int64 little-endian small values => high words zero
    int i64 = ((e32[1] | e32[3] | e32[5] | e32[7]) == 0) ? 1 : 0;
    // bf16: EVEN 16-bit halves are bf16 normals (exponent-banded);
    // f32:  even halves are low mantissa bits (uniform)
    const unsigned short* h = (const unsigned short*)x;
    int cnt = 0;
    for (int i = 0; i < 32; ++i) {
        unsigned b = (h[2 * i] >> 8) & 0x7F;
        if (b >= 0x3C && b <= 0x42) cnt++;
    }
    flags[0] = i64;
    flags[1] = (cnt >= 16) ? 1 : 0;
}

// ---- convert x + all weight tensors to one contiguous f32 block ----
struct CvtArgs {
    const void* src[13];
    int off[13];   // start offset (floats) of tensor k in output; ascending
    int total;
};

__global__ void cvt_all_kernel(CvtArgs a, float* __restrict__ out,
                               const int* __restrict__ flags) {
    const int bf = flags[1];
    for (int idx = blockIdx.x * blockDim.x + threadIdx.x; idx < a.total;
         idx += gridDim.x * blockDim.x) {
        int t = 0;
        for (int k = 1; k < 13; ++k) if (idx >= a.off[k]) t = k;
        int i = idx - a.off[t];
        float v = bf ? __bfloat162float(((const __hip_bfloat16*)a.src[t])[i])
                     : ((const float*)a.src[t])[i];
        out[idx] = v;
    }
}

__global__ void cvt_batch_kernel(const void* __restrict__ in, int* __restrict__ out,
                                 int n, const int* __restrict__ flags) {
    int i = blockIdx.x * blockDim.x + threadIdx.x;
    if (i >= n) return;
    out[i] = flags[0] ? (int)((const long long*)in)[i] : ((const int*)in)[i];
}

__device__ __forceinline__ int eidx_read(const void* eidx, long long i, int is64) {
    return is64 ? (int)((const long long*)eidx)[i] : ((const int*)eidx)[i];
}

// ---- degree count over dst ----
__global__ void deg_kernel(const void* __restrict__ eidx, int E,
                           int* __restrict__ cnt, const int* __restrict__ flags) {
    int i = blockIdx.x * blockDim.x + threadIdx.x;
    if (i < E) {
        int d = eidx_read(eidx, (long long)E + i, flags[0]);
        atomicAdd(&cnt[d], 1);
    }
}

__global__ void dinv_kernel(const int* __restrict__ cnt, float* __restrict__ dinv, int N) {
    int i = blockIdx.x * blockDim.x + threadIdx.x;
    if (i < N) dinv[i] = rsqrtf((float)cnt[i] + 1.0f);
}

// ---- xw = act(h) @ W ; agg = xw*dinv^2 + b ----
// In-place (agg==hin) is ONLY safe when K==F (per-block read/write ranges coincide).
template<int K, int F, int ELU_IN>
__global__ void gemm_init_kernel(const float* __restrict__ hin,
                                 const float* __restrict__ W,
                                 const float* __restrict__ b,
                                 const float* __restrict__ dinv,
                                 float* __restrict__ xw,
                                 float* __restrict__ agg,
                                 int N) {
    constexpr int NS = 256 / F;           // nodes per block
    __shared__ float hs[NS * K];
    __shared__ float Ws[K * F];
    __shared__ float bs[F];
    const int t = threadIdx.x;
    const int base = blockIdx.x * NS;

    for (int i = t; i < K * F; i += 256) Ws[i] = W[i];
    if (t < F) bs[t] = b[t];
    for (int i = t; i < NS * K; i += 256) {
        int node = base + i / K;
        int k = i % K;
        float v = 0.f;
        if (node < N) {
            v = hin[(size_t)node * K + k];
            if (ELU_IN) v = elu_f(v);
        }
        hs[i] = v;
    }
    __syncthreads();

    const int sub = t / F;
    const int j = t % F;
    const int node = base + sub;
    if (node >= N) return;
    float acc = 0.f;
#pragma unroll
    for (int k = 0; k < K; ++k) acc += hs[sub * K + k] * Ws[k * F + j];
    float di = dinv[node];
    xw[(size_t)node * F + j] = acc;
    agg[(size_t)node * F + j] = acc * di * di + bs[j];
}

// ---- edge scatter: agg[dst] += xw[src] * dinv[src]*dinv[dst] ----
template<int F>
__global__ void scatter_kernel(const void* __restrict__ eidx, int E,
                               const float* __restrict__ dinv,
                               const float* __restrict__ xw,
                               float* __restrict__ agg,
                               const int* __restrict__ flags) {
    unsigned gid = blockIdx.x * blockDim.x + threadIdx.x;
    int e = gid / F;
    int j = gid % F;
    if (e >= E) return;
    int is64 = flags[0];
    int s = eidx_read(eidx, e, is64);
    int d = eidx_read(eidx, (long long)E + e, is64);
    float coef = dinv[s] * dinv[d];
    unsafeAtomicAdd(&agg[(size_t)d * F + j], xw[(size_t)s * F + j] * coef);
}

// ---- pooling: pooled[g][j] = max over nodes of elu(agg[n][j]) ----
__global__ void pool_kernel(const float* __restrict__ agg,
                            const int* __restrict__ batch,
                            unsigned* __restrict__ pooled,
                            int N) {
    unsigned gid = blockIdx.x * blockDim.x + threadIdx.x;
    int node = gid / WIDTH;
    int j = gid % WIDTH;
    if (node >= N) return;
    int g = batch[node];
    float v = elu_f(agg[(size_t)node * WIDTH + j]);
    atomicMax(&pooled[g * WIDTH + j], fmono(v));
}

// ---- FC head: one block (64 threads) per graph ----
__global__ void fc_kernel(const unsigned* __restrict__ pooled,
                          const float* __restrict__ Wall,
                          void* __restrict__ out,
                          const int* __restrict__ flags) {
    __shared__ float g[64], y1[64], y2[32], z[2];
    const int bid = blockIdx.x, t = threadIdx.x;
    g[t] = funmono(pooled[bid * 64 + t]);
    __syncthreads();
    {
        float acc = Wall[OFF_FB1 + t];
        for (int k = 0; k < 64; ++k) acc += g[k] * Wall[OFF_FW1 + k * 64 + t];
        y1[t] = elu_f(acc);
    }
    __syncthreads();
    if (t < 32) {
        float acc = Wall[OFF_FB2 + t];
        for (int k = 0; k < 64; ++k) acc += y1[k] * Wall[OFF_FW2 + k * 32 + t];
        y2[t] = elu_f(acc);
    }
    __syncthreads();
    if (t < 2) {
        float acc = Wall[OFF_FB3 + t];
        for (int k = 0; k < 32; ++k) acc += y2[k] * Wall[OFF_FW3 + k * 2 + t];
        z[t] = acc;
    }
    __syncthreads();
    if (t < 2) {
        float m = fmaxf(z[0], z[1]);
        float l = m + logf(expf(z[0] - m) + expf(z[1] - m));
        float r = z[t] - l;
        if (flags[1]) ((__hip_bfloat16*)out)[bid * 2 + t] = __float2bfloat16(r);
        else          ((float*)out)[bid * 2 + t] = r;
    }
}

extern "C" void kernel_launch(void* const* d_in, const int* in_sizes, int n_in,
                              void* d_out, int out_size, void* d_ws, size_t ws_size,
                              hipStream_t stream) {
    const int N = in_sizes[0] / 2;       // 50000
    const int E = in_sizes[1] / 2;       // 1600000

    const void* x    = d_in[0];
    const void* eidx = d_in[1];
    const void* batch = d_in[2];

    // workspace layout (~33.3 MB)
    char* ws = (char*)d_ws;
    size_t off = 0;
    auto alloc = [&](size_t bytes) { char* p = ws + off; off += (bytes + 255) & ~(size_t)255; return p; };
    int*   flags   = (int*)  alloc(2 * sizeof(int));
    float* xcvt    = (float*)alloc(TOTAL_CVT * sizeof(float));   // x_f32 then weights
    int*   batch32 = (int*)  alloc(N_NODES * sizeof(int));
    int*   cnt     = (int*)  alloc(N_NODES * sizeof(int));
    float* dinv    = (float*)alloc(N_NODES * sizeof(float));
    unsigned* pooled = (unsigned*)alloc(N_GRAPHS * WIDTH * sizeof(unsigned));
    float* bufA    = (float*)alloc((size_t)N_NODES * 32 * sizeof(float));
    float* bufB    = (float*)alloc((size_t)N_NODES * 64 * sizeof(float));
    float* xw      = (float*)alloc((size_t)N_NODES * 64 * sizeof(float));

    float* xf   = xcvt;                 // [N,2] f32
    float* Wall = xcvt + TOTAL_X;       // converted weights

    detect_kernel<<<1, 1, 0, stream>>>(eidx, x, flags);

    CvtArgs ca;
    ca.src[0] = x;        ca.off[0] = 0;
    ca.src[1] = d_in[3];  ca.off[1] = TOTAL_X + OFF_W1;
    ca.src[2] = d_in[4];  ca.off[2] = TOTAL_X + OFF_B1;
    ca.src[3] = d_in[5];  ca.off[3] = TOTAL_X + OFF_W2;
    ca.src[4] = d_in[6];  ca.off[4] = TOTAL_X + OFF_B2;
    ca.src[5] = d_in[7];  ca.off[5] = TOTAL_X + OFF_CW;
    ca.src[6] = d_in[8];  ca.off[6] = TOTAL_X + OFF_CB;
    ca.src[7] = d_in[9];  ca.off[7] = TOTAL_X + OFF_FW1;
    ca.src[8] = d_in[10]; ca.off[8] = TOTAL_X + OFF_FB1;
    ca.src[9] = d_in[11]; ca.off[9] = TOTAL_X + OFF_FW2;
    ca.src[10] = d_in[12]; ca.off[10] = TOTAL_X + OFF_FB2;
    ca.src[11] = d_in[13]; ca.off[11] = TOTAL_X + OFF_FW3;
    ca.src[12] = d_in[14]; ca.off[12] = TOTAL_X + OFF_FB3;
    ca.total = TOTAL_CVT;
    cvt_all_kernel<<<(TOTAL_CVT + 255) / 256, 256, 0, stream>>>(ca, xcvt, flags);
    cvt_batch_kernel<<<(N + 255) / 256, 256, 0, stream>>>(batch, batch32, N, flags);

    hipMemsetAsync(cnt, 0, N_NODES * sizeof(int), stream);
    hipMemsetAsync(pooled, 0, N_GRAPHS * WIDTH * sizeof(unsigned), stream);

    deg_kernel<<<(E + 255) / 256, 256, 0, stream>>>(eidx, E, cnt, flags);
    dinv_kernel<<<(N + 255) / 256, 256, 0, stream>>>(cnt, dinv, N);

    // Layer 1: K=2 -> F=32 (no ELU on raw input), xf -> bufA
    gemm_init_kernel<2, 32, 0><<<(N + 7) / 8, 256, 0, stream>>>(
        xf, Wall + OFF_W1, Wall + OFF_B1, dinv, xw, bufA, N);
    scatter_kernel<32><<<((unsigned)E * 32 + 255) / 256, 256, 0, stream>>>(
        eidx, E, dinv, xw, bufA, flags);

    // Layer 2: K=32 -> F=64, bufA -> bufB (distinct buffers: K!=F in-place races)
    gemm_init_kernel<32, 64, 1><<<(N + 3) / 4, 256, 0, stream>>>(
        bufA, Wall + OFF_W2, Wall + OFF_B2, dinv, xw, bufB, N);
    scatter_kernel<64><<<((unsigned)E * 64 + 255) / 256, 256, 0, stream>>>(
        eidx, E, dinv, xw, bufB, flags);

    // Conv layers 0..3: 64 -> 64, in place on bufB (safe: K==F)
    for (int l = 0; l < 4; ++l) {
        gemm_init_kernel<64, 64, 1><<<(N + 3) / 4, 256, 0, stream>>>(
            bufB, Wall + OFF_CW + (size_t)l * 64 * 64, Wall + OFF_CB + (size_t)l * 64,
            dinv, xw, bufB, N);
        scatter_kernel<64><<<((unsigned)E * 64 + 255) / 256, 256, 0, stream>>>(
            eidx, E, dinv, xw, bufB, flags);
    }

    pool_kernel<<<((unsigned)N * WIDTH + 255) / 256, 256, 0, stream>>>(bufB, batch32, pooled, N);

    fc_kernel<<<N_GRAPHS, 64, 0, stream>>>(pooled, Wall, d_out, flags);
}

// Round 5
// 790.426 us; speedup vs baseline: 3.0666x; 3.0666x over previous
//
#include <hip/hip_runtime.h>
#include <hip/hip_bf16.h>

// GCN: 6 conv layers (2->32->64->64x4), segment-max pool to 512 graphs, FC head.
// Input dtypes DETECTED at runtime (flags in ws): floats f32-or-bf16, ints i32-or-i64.
// Edge aggregation via CSR gather (built once per call) — no float atomics.

#define N_NODES 50000
#define N_GRAPHS 512
#define WIDTH 64

// weight offsets (floats) inside the converted-weights block
#define OFF_W1   0
#define OFF_B1   64
#define OFF_W2   96
#define OFF_B2   2144
#define OFF_CW   2208
#define OFF_CB   18592
#define OFF_FW1  18848
#define OFF_FB1  22944
#define OFF_FW2  23008
#define OFF_FB2  25056
#define OFF_FW3  25088
#define OFF_FB3  25152
#define TOTAL_W  25154
#define TOTAL_X  100000
#define TOTAL_CVT (TOTAL_X + TOTAL_W)

__device__ __forceinline__ float elu_f(float x) {
    return x > 0.f ? x : expm1f(x);
}

__device__ __forceinline__ unsigned fmono(float v) {
    unsigned b = __float_as_uint(v);
    return (b & 0x80000000u) ? ~b : (b | 0x80000000u);
}
__device__ __forceinline__ float funmono(unsigned m) {
    unsigned b = (m & 0x80000000u) ? (m ^ 0x80000000u) : ~m;
    return __uint_as_float(b);
}

// ---- dtype detection: flags[0]=ints-are-int64, flags[1]=floats-are-bf16 ----
__global__ void detect_kernel(const void* __restrict__ eidx,
                              const void* __restrict__ x,
                              int* __restrict__ flags) {
    const int* e32 = (const int*)eidx;
    int i64 = ((e32[1] | e32[3] | e32[5] | e32[7]) == 0) ? 1 : 0;
    const unsigned short* h = (const unsigned short*)x;
    int cnt = 0;
    for (int i = 0; i < 32; ++i) {
        unsigned b = (h[2 * i] >> 8) & 0x7F;
        if (b >= 0x3C && b <= 0x42) cnt++;
    }
    flags[0] = i64;
    flags[1] = (cnt >= 16) ? 1 : 0;
}

// ---- convert x + all weight tensors to one contiguous f32 block ----
struct CvtArgs {
    const void* src[13];
    int off[13];
    int total;
};

__global__ void cvt_all_kernel(CvtArgs a, float* __restrict__ out,
                               const int* __restrict__ flags) {
    const int bf = flags[1];
    for (int idx = blockIdx.x * blockDim.x + threadIdx.x; idx < a.total;
         idx += gridDim.x * blockDim.x) {
        int t = 0;
        for (int k = 1; k < 13; ++k) if (idx >= a.off[k]) t = k;
        int i = idx - a.off[t];
        float v = bf ? __bfloat162float(((const __hip_bfloat16*)a.src[t])[i])
                     : ((const float*)a.src[t])[i];
        out[idx] = v;
    }
}

__global__ void cvt_batch_kernel(const void* __restrict__ in, int* __restrict__ out,
                                 int n, const int* __restrict__ flags) {
    int i = blockIdx.x * blockDim.x + threadIdx.x;
    if (i >= n) return;
    out[i] = flags[0] ? (int)((const long long*)in)[i] : ((const int*)in)[i];
}

__device__ __forceinline__ int eidx_read(const void* eidx, long long i, int is64) {
    return is64 ? (int)((const long long*)eidx)[i] : ((const int*)eidx)[i];
}

// ---- degree count over dst ----
__global__ void deg_kernel(const void* __restrict__ eidx, int E,
                           int* __restrict__ cnt, const int* __restrict__ flags) {
    int i = blockIdx.x * blockDim.x + threadIdx.x;
    if (i < E) {
        int d = eidx_read(eidx, (long long)E + i, flags[0]);
        atomicAdd(&cnt[d], 1);
    }
}

__global__ void dinv_kernel(const int* __restrict__ cnt, float* __restrict__ dinv, int N) {
    int i = blockIdx.x * blockDim.x + threadIdx.x;
    if (i < N) dinv[i] = rsqrtf((float)cnt[i] + 1.0f);
}

// ---- CSR build: 3-step exclusive scan of cnt -> rowPtr, then edge fill ----
__global__ void scan_a_kernel(const int* __restrict__ cnt, int* __restrict__ rowPtr,
                              int* __restrict__ bsum, int N) {
    __shared__ int s[256];
    int i = blockIdx.x * 256 + threadIdx.x;
    int v = (i < N) ? cnt[i] : 0;
    s[threadIdx.x] = v;
    __syncthreads();
    for (int o = 1; o < 256; o <<= 1) {
        int t = (threadIdx.x >= o) ? s[threadIdx.x - o] : 0;
        __syncthreads();
        s[threadIdx.x] += t;
        __syncthreads();
    }
    if (i < N) rowPtr[i] = s[threadIdx.x] - v;   // block-local exclusive
    if (threadIdx.x == 255) bsum[blockIdx.x] = s[255];
}

__global__ void scan_b_kernel(int* __restrict__ bsum, int NB) {
    __shared__ int s[256];
    int v = (threadIdx.x < NB) ? bsum[threadIdx.x] : 0;
    s[threadIdx.x] = v;
    __syncthreads();
    for (int o = 1; o < 256; o <<= 1) {
        int t = (threadIdx.x >= o) ? s[threadIdx.x - o] : 0;
        __syncthreads();
        s[threadIdx.x] += t;
        __syncthreads();
    }
    if (threadIdx.x < NB) bsum[threadIdx.x] = s[threadIdx.x] - v;  // exclusive
}

__global__ void scan_c_kernel(int* __restrict__ rowPtr, const int* __restrict__ bsum,
                              int* __restrict__ cursor, int N, int E) {
    int i = blockIdx.x * 256 + threadIdx.x;
    if (i < N) {
        int v = rowPtr[i] + bsum[i >> 8];
        rowPtr[i] = v;
        cursor[i] = v;
    } else if (i == N) {
        rowPtr[N] = E;
    }
}

__global__ void fill_csr_kernel(const void* __restrict__ eidx, int E,
                                int* __restrict__ cursor, int* __restrict__ csr_src,
                                const int* __restrict__ flags) {
    int e = blockIdx.x * blockDim.x + threadIdx.x;
    if (e >= E) return;
    int is64 = flags[0];
    int s = eidx_read(eidx, e, is64);
    int d = eidx_read(eidx, (long long)E + e, is64);
    int pos = atomicAdd(&cursor[d], 1);
    csr_src[pos] = s;
}

// ---- xwp = (act(h) @ W) * dinv[row] ----
template<int K, int F, int ELU_IN>
__global__ void gemm_xw_kernel(const float* __restrict__ hin,
                               const float* __restrict__ W,
                               const float* __restrict__ dinv,
                               float* __restrict__ xwp,
                               int N) {
    constexpr int NS = 256 / F;           // nodes per block
    __shared__ float hs[NS * K];
    __shared__ float Ws[K * F];
    const int t = threadIdx.x;
    const int base = blockIdx.x * NS;

    for (int i = t; i < K * F; i += 256) Ws[i] = W[i];
    for (int i = t; i < NS * K; i += 256) {
        int node = base + i / K;
        int k = i % K;
        float v = 0.f;
        if (node < N) {
            v = hin[(size_t)node * K + k];
            if (ELU_IN) v = elu_f(v);
        }
        hs[i] = v;
    }
    __syncthreads();

    const int sub = t / F;
    const int j = t % F;
    const int node = base + sub;
    if (node >= N) return;
    float acc = 0.f;
#pragma unroll
    for (int k = 0; k < K; ++k) acc += hs[sub * K + k] * Ws[k * F + j];
    xwp[(size_t)node * F + j] = acc * dinv[node];
}

// ---- gather: agg[d][j] = dinv[d]*(sum_{s in N(d)} xwp[s][j] + xwp[d][j]) + b[j] ----
template<int F>
__global__ void gather_kernel(const int* __restrict__ rowPtr,
                              const int* __restrict__ csr_src,
                              const float* __restrict__ xwp,
                              const float* __restrict__ dinv,
                              const float* __restrict__ bias,
                              float* __restrict__ agg, int N) {
    unsigned gid = blockIdx.x * blockDim.x + threadIdx.x;
    int node = gid / F;
    int j = gid % F;
    if (node >= N) return;
    int r0 = rowPtr[node], r1 = rowPtr[node + 1];
    float a0 = xwp[(size_t)node * F + j];   // self-loop term
    float a1 = 0.f, a2 = 0.f, a3 = 0.f;
    int e = r0;
    for (; e + 4 <= r1; e += 4) {
        int s0 = csr_src[e];
        int s1 = csr_src[e + 1];
        int s2 = csr_src[e + 2];
        int s3 = csr_src[e + 3];
        a0 += xwp[(size_t)s0 * F + j];
        a1 += xwp[(size_t)s1 * F + j];
        a2 += xwp[(size_t)s2 * F + j];
        a3 += xwp[(size_t)s3 * F + j];
    }
    for (; e < r1; ++e) a0 += xwp[(size_t)csr_src[e] * F + j];
    agg[(size_t)node * F + j] = ((a0 + a1) + (a2 + a3)) * dinv[node] + bias[j];
}

// ---- pooling: pooled[g][j] = max over nodes of elu(agg[n][j]) ----
__global__ void pool_kernel(const float* __restrict__ agg,
                            const int* __restrict__ batch,
                            unsigned* __restrict__ pooled,
                            int N) {
    unsigned gid = blockIdx.x * blockDim.x + threadIdx.x;
    int node = gid / WIDTH;
    int j = gid % WIDTH;
    if (node >= N) return;
    int g = batch[node];
    float v = elu_f(agg[(size_t)node * WIDTH + j]);
    atomicMax(&pooled[g * WIDTH + j], fmono(v));
}

// ---- FC head: one block (64 threads) per graph ----
__global__ void fc_kernel(const unsigned* __restrict__ pooled,
                          const float* __restrict__ Wall,
                          void* __restrict__ out,
                          const int* __restrict__ flags) {
    __shared__ float g[64], y1[64], y2[32], z[2];
    const int bid = blockIdx.x, t = threadIdx.x;
    g[t] = funmono(pooled[bid * 64 + t]);
    __syncthreads();
    {
        float acc = Wall[OFF_FB1 + t];
        for (int k = 0; k < 64; ++k) acc += g[k] * Wall[OFF_FW1 + k * 64 + t];
        y1[t] = elu_f(acc);
    }
    __syncthreads();
    if (t < 32) {
        float acc = Wall[OFF_FB2 + t];
        for (int k = 0; k < 64; ++k) acc += y1[k] * Wall[OFF_FW2 + k * 32 + t];
        y2[t] = elu_f(acc);
    }
    __syncthreads();
    if (t < 2) {
        float acc = Wall[OFF_FB3 + t];
        for (int k = 0; k < 32; ++k) acc += y2[k] * Wall[OFF_FW3 + k * 2 + t];
        z[t] = acc;
    }
    __syncthreads();
    if (t < 2) {
        float m = fmaxf(z[0], z[1]);
        float l = m + logf(expf(z[0] - m) + expf(z[1] - m));
        float r = z[t] - l;
        if (flags[1]) ((__hip_bfloat16*)out)[bid * 2 + t] = __float2bfloat16(r);
        else          ((float*)out)[bid * 2 + t] = r;
    }
}

extern "C" void kernel_launch(void* const* d_in, const int* in_sizes, int n_in,
                              void* d_out, int out_size, void* d_ws, size_t ws_size,
                              hipStream_t stream) {
    const int N = in_sizes[0] / 2;       // 50000
    const int E = in_sizes[1] / 2;       // 1600000
    const int NB = (N + 255) / 256;      // scan blocks (196 <= 256)

    const void* x    = d_in[0];
    const void* eidx = d_in[1];
    const void* batch = d_in[2];

    // workspace layout (~33.9 MB)
    char* ws = (char*)d_ws;
    size_t off = 0;
    auto alloc = [&](size_t bytes) { char* p = ws + off; off += (bytes + 255) & ~(size_t)255; return p; };
    int*   flags   = (int*)  alloc(2 * sizeof(int));
    float* xcvt    = (float*)alloc(TOTAL_CVT * sizeof(float));
    int*   batch32 = (int*)  alloc(N_NODES * sizeof(int));
    int*   cnt     = (int*)  alloc(N_NODES * sizeof(int));
    float* dinv    = (float*)alloc(N_NODES * sizeof(float));
    int*   rowPtr  = (int*)  alloc((N_NODES + 1) * sizeof(int));
    int*   cursor  = (int*)  alloc(N_NODES * sizeof(int));
    int*   bsum    = (int*)  alloc(256 * sizeof(int));
    unsigned* pooled = (unsigned*)alloc(N_GRAPHS * WIDTH * sizeof(unsigned));
    int*   csr_src = (int*)  alloc((size_t)E * sizeof(int));            // 6.4 MB
    float* bufB    = (float*)alloc((size_t)N_NODES * 64 * sizeof(float)); // 12.8 MB (h/agg)
    float* xw      = (float*)alloc((size_t)N_NODES * 64 * sizeof(float)); // 12.8 MB (xwp)

    float* xf   = xcvt;
    float* Wall = xcvt + TOTAL_X;

    detect_kernel<<<1, 1, 0, stream>>>(eidx, x, flags);

    CvtArgs ca;
    ca.src[0] = x;        ca.off[0] = 0;
    ca.src[1] = d_in[3];  ca.off[1] = TOTAL_X + OFF_W1;
    ca.src[2] = d_in[4];  ca.off[2] = TOTAL_X + OFF_B1;
    ca.src[3] = d_in[5];  ca.off[3] = TOTAL_X + OFF_W2;
    ca.src[4] = d_in[6];  ca.off[4] = TOTAL_X + OFF_B2;
    ca.src[5] = d_in[7];  ca.off[5] = TOTAL_X + OFF_CW;
    ca.src[6] = d_in[8];  ca.off[6] = TOTAL_X + OFF_CB;
    ca.src[7] = d_in[9];  ca.off[7] = TOTAL_X + OFF_FW1;
    ca.src[8] = d_in[10]; ca.off[8] = TOTAL_X + OFF_FB1;
    ca.src[9] = d_in[11]; ca.off[9] = TOTAL_X + OFF_FW2;
    ca.src[10] = d_in[12]; ca.off[10] = TOTAL_X + OFF_FB2;
    ca.src[11] = d_in[13]; ca.off[11] = TOTAL_X + OFF_FW3;
    ca.src[12] = d_in[14]; ca.off[12] = TOTAL_X + OFF_FB3;
    ca.total = TOTAL_CVT;
    cvt_all_kernel<<<(TOTAL_CVT + 255) / 256, 256, 0, stream>>>(ca, xcvt, flags);
    cvt_batch_kernel<<<(N + 255) / 256, 256, 0, stream>>>(batch, batch32, N, flags);

    hipMemsetAsync(cnt, 0, N_NODES * sizeof(int), stream);
    hipMemsetAsync(pooled, 0, N_GRAPHS * WIDTH * sizeof(unsigned), stream);

    deg_kernel<<<(E + 255) / 256, 256, 0, stream>>>(eidx, E, cnt, flags);
    dinv_kernel<<<(N + 255) / 256, 256, 0, stream>>>(cnt, dinv, N);

    // CSR build
    scan_a_kernel<<<NB, 256, 0, stream>>>(cnt, rowPtr, bsum, N);
    scan_b_kernel<<<1, 256, 0, stream>>>(bsum, NB);
    scan_c_kernel<<<(N + 1 + 255) / 256, 256, 0, stream>>>(rowPtr, bsum, cursor, N, E);
    fill_csr_kernel<<<(E + 255) / 256, 256, 0, stream>>>(eidx, E, cursor, csr_src, flags);

    // Layer 1: K=2 -> F=32
    gemm_xw_kernel<2, 32, 0><<<(N + 7) / 8, 256, 0, stream>>>(xf, Wall + OFF_W1, dinv, xw, N);
    gather_kernel<32><<<((unsigned)N * 32 + 255) / 256, 256, 0, stream>>>(
        rowPtr, csr_src, xw, dinv, Wall + OFF_B1, bufB, N);

    // Layer 2: K=32 -> F=64
    gemm_xw_kernel<32, 64, 1><<<(N + 3) / 4, 256, 0, stream>>>(bufB, Wall + OFF_W2, dinv, xw, N);
    gather_kernel<64><<<((unsigned)N * 64 + 255) / 256, 256, 0, stream>>>(
        rowPtr, csr_src, xw, dinv, Wall + OFF_B2, bufB, N);

    // Conv layers 0..3: 64 -> 64
    for (int l = 0; l < 4; ++l) {
        gemm_xw_kernel<64, 64, 1><<<(N + 3) / 4, 256, 0, stream>>>(
            bufB, Wall + OFF_CW + (size_t)l * 64 * 64, dinv, xw, N);
        gather_kernel<64><<<((unsigned)N * 64 + 255) / 256, 256, 0, stream>>>(
            rowPtr, csr_src, xw, dinv, Wall + OFF_CB + (size_t)l * 64, bufB, N);
    }

    pool_kernel<<<((unsigned)N * WIDTH + 255) / 256, 256, 0, stream>>>(bufB, batch32, pooled, N);

    fc_kernel<<<N_GRAPHS, 64, 0, stream>>>(pooled, Wall, d_out, flags);
}